// Round 8
// baseline (168.219 us; speedup 1.0000x reference)
//
#include <hip/hip_runtime.h>

#define BB 2
#define CC 64
#define HH 128
#define WW 128
#define HWN (HH*WW)          // 16384
#define CHW (CC*HWN)         // 2^20

// deform tiling
#define BAND_H 4
#define HALO   8             // dilation 5 + bilinear 1 + guard 2; outliers -> global fallback
#define NBAND  (HH / BAND_H) // 32
#define LROWS  (BAND_H + 2 * HALO)     // 20
#define CPB    2
#define XPAD   8
#define XSTR   (WW + 2 * XPAD)         // 144 (zero-padded row)
// interleaved LDS: float2 {ch0,ch1} per texel; 20*144*2 floats = 23040 B

// osum tiling
#define OB_H 16
#define OB_HALO 7
#define OB_ROWS (OB_H + 2 * OB_HALO)   // 30
#define OSTR 144                        // 128 + 2*8 zero-pad cols

// Stage 1: osum = BN(bias(dw1x15)) + BN(bias(dw15x1)) + BN(bias(dw3x3))
// Zero-padded LDS band; thread owns 8 consecutive w-px -> all taps via
// ds_read_b128 (48 per 8 px instead of 312 ds_read_b32).
__global__ __launch_bounds__(256) void osum_kernel(const float* __restrict__ x,
    const float* __restrict__ w1, const float* __restrict__ b1, const float* __restrict__ s1, const float* __restrict__ g1,
    const float* __restrict__ w2, const float* __restrict__ b2, const float* __restrict__ s2, const float* __restrict__ g2,
    const float* __restrict__ w3, const float* __restrict__ b3, const float* __restrict__ s3, const float* __restrict__ g3,
    float* __restrict__ osum)
{
    __shared__ float xs[OB_ROWS * OSTR];   // 17280 B
    int bid  = blockIdx.x;                 // < BB*CC*8
    int band = bid & 7;
    int bc   = bid >> 3;
    int c    = bc & (CC - 1);
    int bs   = band * OB_H;
    int r_lo_v = bs - OB_HALO;             // virtual (may be <0)

    for (int i = threadIdx.x; i < (OB_ROWS * OSTR) / 4; i += 256)
        ((float4*)xs)[i] = make_float4(0.f, 0.f, 0.f, 0.f);
    __syncthreads();

    int gstart = r_lo_v < 0 ? 0 : r_lo_v;
    int gend   = r_lo_v + OB_ROWS; if (gend > HH) gend = HH;
    int nitems = (gend - gstart) * (WW / 4);
    const float* xp = x + (size_t)bc * HWN;
    for (int i = threadIdx.x; i < nitems; i += 256) {
        int r = i >> 5, col4 = i & 31;
        int g = gstart + r;
        int lr = g - r_lo_v;
        ((float4*)xs)[lr * (OSTR / 4) + 2 + col4] = ((const float4*)(xp + g * WW))[col4];
    }
    __syncthreads();

    float W1[15], W2[15], W3[9];
    #pragma unroll
    for (int k = 0; k < 15; ++k) { W1[k] = w1[c * 15 + k]; W2[k] = w2[c * 15 + k]; }
    #pragma unroll
    for (int k = 0; k < 9; ++k) W3[k] = w3[c * 9 + k];
    float bb1 = b1[c], ss1 = s1[c], gg1 = g1[c];
    float bb2 = b2[c], ss2 = s2[c], gg2 = g2[c];
    float bb3 = b3[c], ss3 = s3[c], gg3 = g3[c];

    const float4* XS4 = (const float4*)xs;
    int oct = threadIdx.x & 15;            // w-octet
    int row = threadIdx.x >> 4;            // 0..15
    int w0  = oct * 8;
    int lr  = row + OB_HALO;               // 7..22
    int h   = bs + row;

    // horizontal window: padded cols [w0, w0+24) = orig [w0-8, w0+16)
    float hb[24];
    #pragma unroll
    for (int t = 0; t < 6; ++t) {
        float4 q = XS4[lr * (OSTR / 4) + 2 * oct + t];
        hb[4*t] = q.x; hb[4*t+1] = q.y; hb[4*t+2] = q.z; hb[4*t+3] = q.w;
    }
    float a1[8];
    #pragma unroll
    for (int j = 0; j < 8; ++j) {
        float s = 0.f;
        #pragma unroll
        for (int k = 0; k < 15; ++k) s += hb[j + 1 + k] * W1[k];   // tap w0+j+k-7
        a1[j] = s;
    }

    // vertical: 15 rows x 2 float4 at center cols [w0, w0+8)
    float a2[8] = {0.f,0.f,0.f,0.f,0.f,0.f,0.f,0.f};
    #pragma unroll
    for (int k = 0; k < 15; ++k) {
        float4 qa = XS4[(lr + k - 7) * (OSTR / 4) + 2 + 2 * oct];
        float4 qb = XS4[(lr + k - 7) * (OSTR / 4) + 3 + 2 * oct];
        a2[0] += qa.x * W2[k]; a2[1] += qa.y * W2[k]; a2[2] += qa.z * W2[k]; a2[3] += qa.w * W2[k];
        a2[4] += qb.x * W2[k]; a2[5] += qb.y * W2[k]; a2[6] += qb.z * W2[k]; a2[7] += qb.w * W2[k];
    }

    // 3x3: rows lr-1..lr+1, padded cols [w0+4-8 .. w0+12+8) via 4 float4/row
    float a3[8] = {0.f,0.f,0.f,0.f,0.f,0.f,0.f,0.f};
    #pragma unroll
    for (int kh = 0; kh < 3; ++kh) {
        float m[16];
        #pragma unroll
        for (int t = 0; t < 4; ++t) {
            float4 q = XS4[(lr + kh - 1) * (OSTR / 4) + 1 + 2 * oct + t];
            m[4*t] = q.x; m[4*t+1] = q.y; m[4*t+2] = q.z; m[4*t+3] = q.w;
        }
        #pragma unroll
        for (int j = 0; j < 8; ++j)
            #pragma unroll
            for (int kw = 0; kw < 3; ++kw)
                a3[j] += m[j + kw + 3] * W3[kh * 3 + kw];   // tap col (8+w0+j)+(kw-1)
    }

    float o[8];
    #pragma unroll
    for (int j = 0; j < 8; ++j)
        o[j] = (a1[j] + bb1) * ss1 + gg1
             + (a2[j] + bb2) * ss2 + gg2
             + (a3[j] + bb3) * ss3 + gg3;
    float* dst = osum + (size_t)bc * HWN + h * WW + w0;
    ((float4*)dst)[0] = make_float4(o[0], o[1], o[2], o[3]);
    ((float4*)dst)[1] = make_float4(o[4], o[5], o[6], o[7]);
}

// Stage 2 (LDS-tiled, 64-px tiles -> 512 blocks): off[b,j,hw] PLANAR
__global__ __launch_bounds__(256) void off_kernel(const float* __restrict__ osum,
    const float* __restrict__ balw, const float* __restrict__ balb,
    const float* __restrict__ s4, const float* __restrict__ g4,
    float* __restrict__ off)
{
    __shared__ float ls[CC * 64];   // 16 KB
    int bid = blockIdx.x;           // < 512
    int b   = bid >> 8;
    int hw0 = (bid & 255) * 64;

    const float* src = osum + (size_t)b * CHW + hw0;
    #pragma unroll
    for (int i = 0; i < 4; ++i) {
        int idx = threadIdx.x + i * 256;      // < 1024 float4
        int row = idx >> 4, col4 = idx & 15;
        ((float4*)ls)[row * 16 + col4] = *(const float4*)(src + (size_t)row * HWN + col4 * 4);
    }
    __syncthreads();

    int px = threadIdx.x & 63;
    int og = __builtin_amdgcn_readfirstlane((int)(threadIdx.x >> 6));  // 0..3
    int start = (og < 2) ? og * 5 : 10 + (og - 2) * 4;
    int cnt   = (og < 2) ? 5 : 4;

    float acc[5] = {0.f, 0.f, 0.f, 0.f, 0.f};
    for (int ic = 0; ic < CC; ++ic) {
        float v = ls[ic * 64 + px];
        #pragma unroll
        for (int j = 0; j < 5; ++j)
            if (j < cnt) acc[j] += v * balw[(start + j) * CC + ic];  // uniform -> s_load
    }
    #pragma unroll
    for (int j = 0; j < 5; ++j)
        if (j < cnt) {
            int oc = start + j;
            off[(size_t)b * (18 * HWN) + (size_t)oc * HWN + hw0 + px] =
                (acc[j] + balb[oc]) * s4[oc] + g4[oc];
        }
}

// zero-padded global gather (exact: reference mask*clamp == zero-pad sampling)
__device__ __forceinline__ float gz(const float* __restrict__ xp, int y, int x) {
    return ((unsigned)y < (unsigned)HH && (unsigned)x < (unsigned)WW) ? xp[y * WW + x] : 0.f;
}

// Stage 3: deformable gather. 2 ch/block (interleaved LDS), zero-padded tile,
// frac shared across dilations. BAND_H=4 -> 2048 blocks (grid-limit fix).
// bid low 5 bits = band -> XCD = band%8 locality.
__global__ __launch_bounds__(256) void deform_kernel(
    const float* __restrict__ x,
    const float* __restrict__ off,
    const float* __restrict__ dw2, const float* __restrict__ dw3,
    const float* __restrict__ dw4, const float* __restrict__ dw5,
    float* __restrict__ pre)
{
    __shared__ float xs[LROWS * XSTR * CPB];   // 23040 B, float2-interleaved

    int bid  = blockIdx.x;                     // < 2048
    int band = bid & (NBAND - 1);
    int bcp  = bid >> 5;
    int cp   = bcp & 31;
    int b    = bcp >> 5;
    int c0   = cp * CPB;
    int bc0  = b * CC + c0;

    int r_lo_v = band * BAND_H - HALO;

    for (int i = threadIdx.x; i < (LROWS * XSTR * CPB) / 4; i += 256)
        ((float4*)xs)[i] = make_float4(0.f, 0.f, 0.f, 0.f);
    __syncthreads();

    int gstart = r_lo_v < 0 ? 0 : r_lo_v;
    int gend   = r_lo_v + LROWS; if (gend > HH) gend = HH;
    int nitems = (gend - gstart) * (WW / 4);
    const float* xp0 = x + (size_t)bc0 * HWN;
    const float* xp1 = xp0 + HWN;
    for (int i = threadIdx.x; i < nitems; i += 256) {
        int r = i >> 5, col4 = i & 31;
        int g = gstart + r;
        int lr = g - r_lo_v;
        float4 q0 = ((const float4*)(xp0 + g * WW))[col4];
        float4 q1 = ((const float4*)(xp1 + g * WW))[col4];
        ((float4*)xs)[lr * (XSTR / 2) + XPAD / 2 + col4 * 2]     = make_float4(q0.x, q1.x, q0.y, q1.y);
        ((float4*)xs)[lr * (XSTR / 2) + XPAD / 2 + col4 * 2 + 1] = make_float4(q0.z, q1.z, q0.w, q1.w);
    }
    __syncthreads();

    const float2* XS2 = (const float2*)xs;
    const float* offb = off + (size_t)b * (18 * HWN);

    #pragma unroll 1
    for (int chunk = 0; chunk < (BAND_H * WW) / 256; ++chunk) {
        int p = band * (BAND_H * WW) + chunk * 256 + (int)threadIdx.x;
        float hf = (float)(p >> 7);
        float wf = (float)(p & (WW - 1));

        float oy[9], ox[9];
        #pragma unroll
        for (int k = 0; k < 9; ++k) {                   // planar, fully coalesced
            oy[k] = offb[((size_t)(2 * k) << 14) + p];
            ox[k] = offb[((size_t)(2 * k + 1) << 14) + p];
        }

        float acc0 = 0.f, acc1 = 0.f;
        #pragma unroll
        for (int k = 0; k < 9; ++k) {
            const int ky = k / 3 - 1, kx = k % 3 - 1;
            float pyb = oy[k] + hf;
            float pxb = ox[k] + wf;
            float y0f = floorf(pyb), x0f = floorf(pxb);
            float wy = pyb - y0f, wx = pxb - x0f;
            int y0g = (int)y0f, x0g = (int)x0f;
            int y0b = y0g - r_lo_v;
            int x0b = x0g + XPAD;
            float cxa = 1.f - wx, cxb = wx;

            const int dkyLo = (ky < 0) ? -5 : (ky > 0 ? 2 : 0);
            const int dkyHi = (ky < 0) ? -2 : (ky > 0 ? 5 : 0);
            const int dkxLo = (kx < 0) ? -5 : (kx > 0 ? 2 : 0);
            const int dkxHi = (kx < 0) ? -2 : (kx > 0 ? 5 : 0);
            bool ok = (y0b + dkyLo >= 0) & (y0b + dkyHi <= LROWS - 2)
                    & (x0b + dkxLo >= 0) & (x0b + dkxHi <= XSTR - 2);

            if (ok) {
                #pragma unroll
                for (int di = 0; di < 4; ++di) {
                    const int d = di + 2;
                    int f0 = (y0b + d * ky) * XSTR + (x0b + d * kx);
                    float2 a  = XS2[f0],        bq = XS2[f0 + 1];
                    float2 cq = XS2[f0 + XSTR], dq = XS2[f0 + XSTR + 1];
                    float ra0 = cxa * a.x + cxb * bq.x;
                    float rb0 = cxa * cq.x + cxb * dq.x;
                    float ra1 = cxa * a.y + cxb * bq.y;
                    float rb1 = cxa * cq.y + cxb * dq.y;
                    float s0 = ra0 + wy * (rb0 - ra0);
                    float s1 = ra1 + wy * (rb1 - ra1);
                    const float* dwp = (di == 0) ? dw2 : (di == 1) ? dw3 : (di == 2) ? dw4 : dw5;
                    acc0 += s0 * dwp[c0 * 9 + k];        // block-uniform -> s_load
                    acc1 += s1 * dwp[(c0 + 1) * 9 + k];
                }
            } else {                                     // rare outlier: global zero-pad
                #pragma unroll
                for (int di = 0; di < 4; ++di) {
                    const int d = di + 2;
                    int yy = y0g + d * ky, xx = x0g + d * kx;
                    float v00 = gz(xp0, yy, xx),     v01 = gz(xp0, yy, xx + 1);
                    float v10 = gz(xp0, yy + 1, xx), v11 = gz(xp0, yy + 1, xx + 1);
                    float u00 = gz(xp1, yy, xx),     u01 = gz(xp1, yy, xx + 1);
                    float u10 = gz(xp1, yy + 1, xx), u11 = gz(xp1, yy + 1, xx + 1);
                    float s0 = (1.f - wy) * (cxa * v00 + cxb * v01) + wy * (cxa * v10 + cxb * v11);
                    float s1 = (1.f - wy) * (cxa * u00 + cxb * u01) + wy * (cxa * u10 + cxb * u11);
                    const float* dwp = (di == 0) ? dw2 : (di == 1) ? dw3 : (di == 2) ? dw4 : dw5;
                    acc0 += s0 * dwp[c0 * 9 + k];
                    acc1 += s1 * dwp[(c0 + 1) * 9 + k];
                }
            }
        }
        pre[((size_t)bc0 << 14) + p]       = acc0;
        pre[((size_t)(bc0 + 1) << 14) + p] = acc1;
    }
}

// Stage 4 (LDS-tiled): out = (BN(bias(1x1conv(pre, fin_w)))) * x
__global__ __launch_bounds__(256) void final_kernel(const float* __restrict__ pre,
    const float* __restrict__ finw, const float* __restrict__ finb,
    const float* __restrict__ s5, const float* __restrict__ g5,
    const float* __restrict__ x, float* __restrict__ out)
{
    __shared__ float ls[CC * 64];   // 16 KB
    int bid = blockIdx.x;           // < 512
    int b   = bid >> 8;
    int hw0 = (bid & 255) * 64;

    const float* src = pre + (size_t)b * CHW + hw0;
    #pragma unroll
    for (int i = 0; i < 4; ++i) {
        int idx = threadIdx.x + i * 256;      // < 1024 float4
        int row = idx >> 4, col4 = idx & 15;
        ((float4*)ls)[row * 16 + col4] = *(const float4*)(src + (size_t)row * HWN + col4 * 4);
    }
    __syncthreads();

    int hw = threadIdx.x & 63;
    int og = __builtin_amdgcn_readfirstlane((int)(threadIdx.x >> 6));  // 0..3

    float acc[16];
    #pragma unroll
    for (int j = 0; j < 16; ++j) acc[j] = 0.f;
    for (int ic = 0; ic < CC; ++ic) {
        float v = ls[ic * 64 + hw];
        #pragma unroll
        for (int j = 0; j < 16; ++j)
            acc[j] += v * finw[(og * 16 + j) * CC + ic];   // uniform -> s_load
    }
    #pragma unroll
    for (int j = 0; j < 16; ++j) {
        int oc = og * 16 + j;
        size_t oidx = ((size_t)(b * CC + oc) << 14) + hw0 + hw;
        out[oidx] = ((acc[j] + finb[oc]) * s5[oc] + g5[oc]) * x[oidx];
    }
}

extern "C" void kernel_launch(void* const* d_in, const int* in_sizes, int n_in,
                              void* d_out, int out_size, void* d_ws, size_t ws_size,
                              hipStream_t stream) {
    const float* x      = (const float*)d_in[0];
    const float* off1_w = (const float*)d_in[1];
    const float* off1_b = (const float*)d_in[2];
    const float* bn1_s  = (const float*)d_in[3];
    const float* bn1_b  = (const float*)d_in[4];
    const float* off2_w = (const float*)d_in[5];
    const float* off2_b = (const float*)d_in[6];
    const float* bn2_s  = (const float*)d_in[7];
    const float* bn2_b  = (const float*)d_in[8];
    const float* off3_w = (const float*)d_in[9];
    const float* off3_b = (const float*)d_in[10];
    const float* bn3_s  = (const float*)d_in[11];
    const float* bn3_b  = (const float*)d_in[12];
    const float* bal_w  = (const float*)d_in[13];
    const float* bal_b  = (const float*)d_in[14];
    const float* bn4_s  = (const float*)d_in[15];
    const float* bn4_b  = (const float*)d_in[16];
    const float* dw2    = (const float*)d_in[17];
    const float* dw3    = (const float*)d_in[18];
    const float* dw4    = (const float*)d_in[19];
    const float* dw5    = (const float*)d_in[20];
    const float* fin_w  = (const float*)d_in[21];
    const float* fin_b  = (const float*)d_in[22];
    const float* bn5_s  = (const float*)d_in[23];
    const float* bn5_b  = (const float*)d_in[24];

    float* ws   = (float*)d_ws;
    float* osum = ws;                              // 8 MB
    float* off  = ws + (size_t)BB * CHW;           // 2.25 MB (planar)
    float* pre  = off + (size_t)BB * 18 * HWN;     // 8 MB

    float* out = (float*)d_out;

    osum_kernel<<<BB * CC * (HH / OB_H), 256, 0, stream>>>(x,
        off1_w, off1_b, bn1_s, bn1_b,
        off2_w, off2_b, bn2_s, bn2_b,
        off3_w, off3_b, bn3_s, bn3_b, osum);
    off_kernel<<<BB * (HWN / 64), 256, 0, stream>>>(osum, bal_w, bal_b, bn4_s, bn4_b, off);
    deform_kernel<<<BB * (CC / CPB) * NBAND, 256, 0, stream>>>(x, off, dw2, dw3, dw4, dw5, pre);
    final_kernel<<<BB * (HWN / 64), 256, 0, stream>>>(pre, fin_w, fin_b, bn5_s, bn5_b, x, out);
}

// Round 9
// 164.482 us; speedup vs baseline: 1.0227x; 1.0227x over previous
//
#include <hip/hip_runtime.h>

#define BB 2
#define CC 64
#define HH 128
#define WW 128
#define HWN (HH*WW)          // 16384
#define CHW (CC*HWN)         // 2^20

// deform tiling (R7-proven best)
#define BAND_H 8
#define HALO   8             // dilation 5 + bilinear 1 + guard 2; outliers -> global fallback
#define NBAND  (HH / BAND_H) // 16
#define LROWS  (BAND_H + 2 * HALO)     // 24
#define CPB    2
#define XPAD   8
#define XSTR   (WW + 2 * XPAD)         // 144 (zero-padded row)
// interleaved LDS: float2 {ch0,ch1} per texel; 24*144*2 floats = 27648 B

// osum tiling
#define OB_H 16
#define OB_HALO 7
#define OB_ROWS (OB_H + 2 * OB_HALO)   // 30
#define OSTR 144                        // 128 + 2*8 zero-pad cols

// Stage 1: osum = BN(bias(dw1x15)) + BN(bias(dw15x1)) + BN(bias(dw3x3))
// Zero-padded LDS band; thread owns 8 consecutive w-px -> all taps via
// ds_read_b128 (48 per 8 px instead of 312 ds_read_b32).
__global__ __launch_bounds__(256) void osum_kernel(const float* __restrict__ x,
    const float* __restrict__ w1, const float* __restrict__ b1, const float* __restrict__ s1, const float* __restrict__ g1,
    const float* __restrict__ w2, const float* __restrict__ b2, const float* __restrict__ s2, const float* __restrict__ g2,
    const float* __restrict__ w3, const float* __restrict__ b3, const float* __restrict__ s3, const float* __restrict__ g3,
    float* __restrict__ osum)
{
    __shared__ float xs[OB_ROWS * OSTR];   // 17280 B
    int bid  = blockIdx.x;                 // < BB*CC*8
    int band = bid & 7;
    int bc   = bid >> 3;
    int c    = bc & (CC - 1);
    int bs   = band * OB_H;
    int r_lo_v = bs - OB_HALO;             // virtual (may be <0)

    for (int i = threadIdx.x; i < (OB_ROWS * OSTR) / 4; i += 256)
        ((float4*)xs)[i] = make_float4(0.f, 0.f, 0.f, 0.f);
    __syncthreads();

    int gstart = r_lo_v < 0 ? 0 : r_lo_v;
    int gend   = r_lo_v + OB_ROWS; if (gend > HH) gend = HH;
    int nitems = (gend - gstart) * (WW / 4);
    const float* xp = x + (size_t)bc * HWN;
    for (int i = threadIdx.x; i < nitems; i += 256) {
        int r = i >> 5, col4 = i & 31;
        int g = gstart + r;
        int lr = g - r_lo_v;
        ((float4*)xs)[lr * (OSTR / 4) + 2 + col4] = ((const float4*)(xp + g * WW))[col4];
    }
    __syncthreads();

    float W1[15], W2[15], W3[9];
    #pragma unroll
    for (int k = 0; k < 15; ++k) { W1[k] = w1[c * 15 + k]; W2[k] = w2[c * 15 + k]; }
    #pragma unroll
    for (int k = 0; k < 9; ++k) W3[k] = w3[c * 9 + k];
    float bb1 = b1[c], ss1 = s1[c], gg1 = g1[c];
    float bb2 = b2[c], ss2 = s2[c], gg2 = g2[c];
    float bb3 = b3[c], ss3 = s3[c], gg3 = g3[c];

    const float4* XS4 = (const float4*)xs;
    int oct = threadIdx.x & 15;            // w-octet
    int row = threadIdx.x >> 4;            // 0..15
    int w0  = oct * 8;
    int lr  = row + OB_HALO;               // 7..22
    int h   = bs + row;

    // horizontal window: padded cols [w0, w0+24) = orig [w0-8, w0+16)
    float hb[24];
    #pragma unroll
    for (int t = 0; t < 6; ++t) {
        float4 q = XS4[lr * (OSTR / 4) + 2 * oct + t];
        hb[4*t] = q.x; hb[4*t+1] = q.y; hb[4*t+2] = q.z; hb[4*t+3] = q.w;
    }
    float a1[8];
    #pragma unroll
    for (int j = 0; j < 8; ++j) {
        float s = 0.f;
        #pragma unroll
        for (int k = 0; k < 15; ++k) s += hb[j + 1 + k] * W1[k];   // tap w0+j+k-7
        a1[j] = s;
    }

    // vertical: 15 rows x 2 float4 at center cols [w0, w0+8)
    float a2[8] = {0.f,0.f,0.f,0.f,0.f,0.f,0.f,0.f};
    #pragma unroll
    for (int k = 0; k < 15; ++k) {
        float4 qa = XS4[(lr + k - 7) * (OSTR / 4) + 2 + 2 * oct];
        float4 qb = XS4[(lr + k - 7) * (OSTR / 4) + 3 + 2 * oct];
        a2[0] += qa.x * W2[k]; a2[1] += qa.y * W2[k]; a2[2] += qa.z * W2[k]; a2[3] += qa.w * W2[k];
        a2[4] += qb.x * W2[k]; a2[5] += qb.y * W2[k]; a2[6] += qb.z * W2[k]; a2[7] += qb.w * W2[k];
    }

    // 3x3: rows lr-1..lr+1, padded cols via 4 float4/row
    float a3[8] = {0.f,0.f,0.f,0.f,0.f,0.f,0.f,0.f};
    #pragma unroll
    for (int kh = 0; kh < 3; ++kh) {
        float m[16];
        #pragma unroll
        for (int t = 0; t < 4; ++t) {
            float4 q = XS4[(lr + kh - 1) * (OSTR / 4) + 1 + 2 * oct + t];
            m[4*t] = q.x; m[4*t+1] = q.y; m[4*t+2] = q.z; m[4*t+3] = q.w;
        }
        #pragma unroll
        for (int j = 0; j < 8; ++j)
            #pragma unroll
            for (int kw = 0; kw < 3; ++kw)
                a3[j] += m[j + kw + 3] * W3[kh * 3 + kw];   // tap col (8+w0+j)+(kw-1)
    }

    float o[8];
    #pragma unroll
    for (int j = 0; j < 8; ++j)
        o[j] = (a1[j] + bb1) * ss1 + gg1
             + (a2[j] + bb2) * ss2 + gg2
             + (a3[j] + bb3) * ss3 + gg3;
    float* dst = osum + (size_t)bc * HWN + h * WW + w0;
    ((float4*)dst)[0] = make_float4(o[0], o[1], o[2], o[3]);
    ((float4*)dst)[1] = make_float4(o[4], o[5], o[6], o[7]);
}

// Stage 2 (LDS-tiled, 64-px tiles -> 512 blocks): off[b,j,hw] PLANAR
__global__ __launch_bounds__(256) void off_kernel(const float* __restrict__ osum,
    const float* __restrict__ balw, const float* __restrict__ balb,
    const float* __restrict__ s4, const float* __restrict__ g4,
    float* __restrict__ off)
{
    __shared__ float ls[CC * 64];   // 16 KB
    int bid = blockIdx.x;           // < 512
    int b   = bid >> 8;
    int hw0 = (bid & 255) * 64;

    const float* src = osum + (size_t)b * CHW + hw0;
    #pragma unroll
    for (int i = 0; i < 4; ++i) {
        int idx = threadIdx.x + i * 256;      // < 1024 float4
        int row = idx >> 4, col4 = idx & 15;
        ((float4*)ls)[row * 16 + col4] = *(const float4*)(src + (size_t)row * HWN + col4 * 4);
    }
    __syncthreads();

    int px = threadIdx.x & 63;
    int og = __builtin_amdgcn_readfirstlane((int)(threadIdx.x >> 6));  // 0..3
    int start = (og < 2) ? og * 5 : 10 + (og - 2) * 4;
    int cnt   = (og < 2) ? 5 : 4;

    float acc[5] = {0.f, 0.f, 0.f, 0.f, 0.f};
    for (int ic = 0; ic < CC; ++ic) {
        float v = ls[ic * 64 + px];
        #pragma unroll
        for (int j = 0; j < 5; ++j)
            if (j < cnt) acc[j] += v * balw[(start + j) * CC + ic];  // uniform -> s_load
    }
    #pragma unroll
    for (int j = 0; j < 5; ++j)
        if (j < cnt) {
            int oc = start + j;
            off[(size_t)b * (18 * HWN) + (size_t)oc * HWN + hw0 + px] =
                (acc[j] + balb[oc]) * s4[oc] + g4[oc];
        }
}

// zero-padded global gather (exact: reference mask*clamp == zero-pad sampling)
__device__ __forceinline__ float gz(const float* __restrict__ xp, int y, int x) {
    return ((unsigned)y < (unsigned)HH && (unsigned)x < (unsigned)WW) ? xp[y * WW + x] : 0.f;
}

// Stage 3 (R7-proven): deformable gather. 2 ch/block (interleaved LDS),
// zero-padded tile, frac shared across dilations. BAND_H=8, 1024 blocks.
// bid low 4 bits = band -> XCD = band%8 locality.
__global__ __launch_bounds__(256) void deform_kernel(
    const float* __restrict__ x,
    const float* __restrict__ off,
    const float* __restrict__ dw2, const float* __restrict__ dw3,
    const float* __restrict__ dw4, const float* __restrict__ dw5,
    float* __restrict__ pre)
{
    __shared__ float xs[LROWS * XSTR * CPB];   // 27648 B, float2-interleaved

    int bid  = blockIdx.x;                     // < 1024
    int band = bid & (NBAND - 1);
    int bcp  = bid >> 4;
    int cp   = bcp & 31;
    int b    = bcp >> 5;
    int c0   = cp * CPB;
    int bc0  = b * CC + c0;

    int r_lo_v = band * BAND_H - HALO;

    for (int i = threadIdx.x; i < (LROWS * XSTR * CPB) / 4; i += 256)
        ((float4*)xs)[i] = make_float4(0.f, 0.f, 0.f, 0.f);
    __syncthreads();

    int gstart = r_lo_v < 0 ? 0 : r_lo_v;
    int gend   = r_lo_v + LROWS; if (gend > HH) gend = HH;
    int nitems = (gend - gstart) * (WW / 4);
    const float* xp0 = x + (size_t)bc0 * HWN;
    const float* xp1 = xp0 + HWN;
    for (int i = threadIdx.x; i < nitems; i += 256) {
        int r = i >> 5, col4 = i & 31;
        int g = gstart + r;
        int lr = g - r_lo_v;
        float4 q0 = ((const float4*)(xp0 + g * WW))[col4];
        float4 q1 = ((const float4*)(xp1 + g * WW))[col4];
        ((float4*)xs)[lr * (XSTR / 2) + XPAD / 2 + col4 * 2]     = make_float4(q0.x, q1.x, q0.y, q1.y);
        ((float4*)xs)[lr * (XSTR / 2) + XPAD / 2 + col4 * 2 + 1] = make_float4(q0.z, q1.z, q0.w, q1.w);
    }
    __syncthreads();

    const float2* XS2 = (const float2*)xs;
    const float* offb = off + (size_t)b * (18 * HWN);

    #pragma unroll 1
    for (int chunk = 0; chunk < (BAND_H * WW) / 256; ++chunk) {
        int p = band * (BAND_H * WW) + chunk * 256 + (int)threadIdx.x;
        float hf = (float)(p >> 7);
        float wf = (float)(p & (WW - 1));

        float oy[9], ox[9];
        #pragma unroll
        for (int k = 0; k < 9; ++k) {                   // planar, fully coalesced
            oy[k] = offb[((size_t)(2 * k) << 14) + p];
            ox[k] = offb[((size_t)(2 * k + 1) << 14) + p];
        }

        float acc0 = 0.f, acc1 = 0.f;
        #pragma unroll
        for (int k = 0; k < 9; ++k) {
            const int ky = k / 3 - 1, kx = k % 3 - 1;
            float pyb = oy[k] + hf;
            float pxb = ox[k] + wf;
            float y0f = floorf(pyb), x0f = floorf(pxb);
            float wy = pyb - y0f, wx = pxb - x0f;
            int y0g = (int)y0f, x0g = (int)x0f;
            int y0b = y0g - r_lo_v;
            int x0b = x0g + XPAD;
            float cxa = 1.f - wx, cxb = wx;

            const int dkyLo = (ky < 0) ? -5 : (ky > 0 ? 2 : 0);
            const int dkyHi = (ky < 0) ? -2 : (ky > 0 ? 5 : 0);
            const int dkxLo = (kx < 0) ? -5 : (kx > 0 ? 2 : 0);
            const int dkxHi = (kx < 0) ? -2 : (kx > 0 ? 5 : 0);
            bool ok = (y0b + dkyLo >= 0) & (y0b + dkyHi <= LROWS - 2)
                    & (x0b + dkxLo >= 0) & (x0b + dkxHi <= XSTR - 2);

            if (ok) {
                #pragma unroll
                for (int di = 0; di < 4; ++di) {
                    const int d = di + 2;
                    int f0 = (y0b + d * ky) * XSTR + (x0b + d * kx);
                    float2 a  = XS2[f0],        bq = XS2[f0 + 1];
                    float2 cq = XS2[f0 + XSTR], dq = XS2[f0 + XSTR + 1];
                    float ra0 = cxa * a.x + cxb * bq.x;
                    float rb0 = cxa * cq.x + cxb * dq.x;
                    float ra1 = cxa * a.y + cxb * bq.y;
                    float rb1 = cxa * cq.y + cxb * dq.y;
                    float s0 = ra0 + wy * (rb0 - ra0);
                    float s1 = ra1 + wy * (rb1 - ra1);
                    const float* dwp = (di == 0) ? dw2 : (di == 1) ? dw3 : (di == 2) ? dw4 : dw5;
                    acc0 += s0 * dwp[c0 * 9 + k];        // block-uniform -> s_load
                    acc1 += s1 * dwp[(c0 + 1) * 9 + k];
                }
            } else {                                     // rare outlier: global zero-pad
                #pragma unroll
                for (int di = 0; di < 4; ++di) {
                    const int d = di + 2;
                    int yy = y0g + d * ky, xx = x0g + d * kx;
                    float v00 = gz(xp0, yy, xx),     v01 = gz(xp0, yy, xx + 1);
                    float v10 = gz(xp0, yy + 1, xx), v11 = gz(xp0, yy + 1, xx + 1);
                    float u00 = gz(xp1, yy, xx),     u01 = gz(xp1, yy, xx + 1);
                    float u10 = gz(xp1, yy + 1, xx), u11 = gz(xp1, yy + 1, xx + 1);
                    float s0 = (1.f - wy) * (cxa * v00 + cxb * v01) + wy * (cxa * v10 + cxb * v11);
                    float s1 = (1.f - wy) * (cxa * u00 + cxb * u01) + wy * (cxa * u10 + cxb * u11);
                    const float* dwp = (di == 0) ? dw2 : (di == 1) ? dw3 : (di == 2) ? dw4 : dw5;
                    acc0 += s0 * dwp[c0 * 9 + k];
                    acc1 += s1 * dwp[(c0 + 1) * 9 + k];
                }
            }
        }
        pre[((size_t)bc0 << 14) + p]       = acc0;
        pre[((size_t)(bc0 + 1) << 14) + p] = acc1;
    }
}

// Stage 4 (LDS-tiled): out = (BN(bias(1x1conv(pre, fin_w)))) * x
__global__ __launch_bounds__(256) void final_kernel(const float* __restrict__ pre,
    const float* __restrict__ finw, const float* __restrict__ finb,
    const float* __restrict__ s5, const float* __restrict__ g5,
    const float* __restrict__ x, float* __restrict__ out)
{
    __shared__ float ls[CC * 64];   // 16 KB
    int bid = blockIdx.x;           // < 512
    int b   = bid >> 8;
    int hw0 = (bid & 255) * 64;

    const float* src = pre + (size_t)b * CHW + hw0;
    #pragma unroll
    for (int i = 0; i < 4; ++i) {
        int idx = threadIdx.x + i * 256;      // < 1024 float4
        int row = idx >> 4, col4 = idx & 15;
        ((float4*)ls)[row * 16 + col4] = *(const float4*)(src + (size_t)row * HWN + col4 * 4);
    }
    __syncthreads();

    int hw = threadIdx.x & 63;
    int og = __builtin_amdgcn_readfirstlane((int)(threadIdx.x >> 6));  // 0..3

    float acc[16];
    #pragma unroll
    for (int j = 0; j < 16; ++j) acc[j] = 0.f;
    for (int ic = 0; ic < CC; ++ic) {
        float v = ls[ic * 64 + hw];
        #pragma unroll
        for (int j = 0; j < 16; ++j)
            acc[j] += v * finw[(og * 16 + j) * CC + ic];   // uniform -> s_load
    }
    #pragma unroll
    for (int j = 0; j < 16; ++j) {
        int oc = og * 16 + j;
        size_t oidx = ((size_t)(b * CC + oc) << 14) + hw0 + hw;
        out[oidx] = ((acc[j] + finb[oc]) * s5[oc] + g5[oc]) * x[oidx];
    }
}

extern "C" void kernel_launch(void* const* d_in, const int* in_sizes, int n_in,
                              void* d_out, int out_size, void* d_ws, size_t ws_size,
                              hipStream_t stream) {
    const float* x      = (const float*)d_in[0];
    const float* off1_w = (const float*)d_in[1];
    const float* off1_b = (const float*)d_in[2];
    const float* bn1_s  = (const float*)d_in[3];
    const float* bn1_b  = (const float*)d_in[4];
    const float* off2_w = (const float*)d_in[5];
    const float* off2_b = (const float*)d_in[6];
    const float* bn2_s  = (const float*)d_in[7];
    const float* bn2_b  = (const float*)d_in[8];
    const float* off3_w = (const float*)d_in[9];
    const float* off3_b = (const float*)d_in[10];
    const float* bn3_s  = (const float*)d_in[11];
    const float* bn3_b  = (const float*)d_in[12];
    const float* bal_w  = (const float*)d_in[13];
    const float* bal_b  = (const float*)d_in[14];
    const float* bn4_s  = (const float*)d_in[15];
    const float* bn4_b  = (const float*)d_in[16];
    const float* dw2    = (const float*)d_in[17];
    const float* dw3    = (const float*)d_in[18];
    const float* dw4    = (const float*)d_in[19];
    const float* dw5    = (const float*)d_in[20];
    const float* fin_w  = (const float*)d_in[21];
    const float* fin_b  = (const float*)d_in[22];
    const float* bn5_s  = (const float*)d_in[23];
    const float* bn5_b  = (const float*)d_in[24];

    float* ws   = (float*)d_ws;
    float* osum = ws;                              // 8 MB
    float* off  = ws + (size_t)BB * CHW;           // 2.25 MB (planar)
    float* pre  = off + (size_t)BB * 18 * HWN;     // 8 MB

    float* out = (float*)d_out;

    osum_kernel<<<BB * CC * (HH / OB_H), 256, 0, stream>>>(x,
        off1_w, off1_b, bn1_s, bn1_b,
        off2_w, off2_b, bn2_s, bn2_b,
        off3_w, off3_b, bn3_s, bn3_b, osum);
    off_kernel<<<BB * (HWN / 64), 256, 0, stream>>>(osum, bal_w, bal_b, bn4_s, bn4_b, off);
    deform_kernel<<<BB * (CC / CPB) * NBAND, 256, 0, stream>>>(x, off, dw2, dw3, dw4, dw5, pre);
    final_kernel<<<BB * (HWN / 64), 256, 0, stream>>>(pre, fin_w, fin_b, bn5_s, bn5_b, x, out);
}

// Round 10
// 163.972 us; speedup vs baseline: 1.0259x; 1.0031x over previous
//
#include <hip/hip_runtime.h>

#define BB 2
#define CC 64
#define HH 128
#define WW 128
#define HWN (HH*WW)          // 16384
#define CHW (CC*HWN)         // 2^20

// deform tiling (R7-proven best)
#define BAND_H 8
#define HALO   8             // dilation 5 + bilinear 1 + guard 2; outliers -> global fallback
#define NBAND  (HH / BAND_H) // 16
#define LROWS  (BAND_H + 2 * HALO)     // 24
#define CPB    2
#define XPAD   8
#define XSTR   (WW + 2 * XPAD)         // 144 texels (zero-padded row)
// interleaved LDS: float2 {ch0,ch1} per texel; 24*144*8B = 27648 B

// osum tiling
#define OB_H 16
#define OB_HALO 7
#define OB_ROWS (OB_H + 2 * OB_HALO)   // 30
#define OSTR 144                        // 128 + 2*8 zero-pad cols

// Stage 1: osum = BN(bias(dw1x15)) + BN(bias(dw15x1)) + BN(bias(dw3x3))
// Zero-padded LDS band; thread owns 8 consecutive w-px -> ds_read_b128 taps.
__global__ __launch_bounds__(256) void osum_kernel(const float* __restrict__ x,
    const float* __restrict__ w1, const float* __restrict__ b1, const float* __restrict__ s1, const float* __restrict__ g1,
    const float* __restrict__ w2, const float* __restrict__ b2, const float* __restrict__ s2, const float* __restrict__ g2,
    const float* __restrict__ w3, const float* __restrict__ b3, const float* __restrict__ s3, const float* __restrict__ g3,
    float* __restrict__ osum)
{
    __shared__ float xs[OB_ROWS * OSTR];   // 17280 B
    int bid  = blockIdx.x;                 // < BB*CC*8
    int band = bid & 7;
    int bc   = bid >> 3;
    int c    = bc & (CC - 1);
    int bs   = band * OB_H;
    int r_lo_v = bs - OB_HALO;             // virtual (may be <0)

    for (int i = threadIdx.x; i < (OB_ROWS * OSTR) / 4; i += 256)
        ((float4*)xs)[i] = make_float4(0.f, 0.f, 0.f, 0.f);
    __syncthreads();

    int gstart = r_lo_v < 0 ? 0 : r_lo_v;
    int gend   = r_lo_v + OB_ROWS; if (gend > HH) gend = HH;
    int nitems = (gend - gstart) * (WW / 4);
    const float* xp = x + (size_t)bc * HWN;
    for (int i = threadIdx.x; i < nitems; i += 256) {
        int r = i >> 5, col4 = i & 31;
        int g = gstart + r;
        int lr = g - r_lo_v;
        ((float4*)xs)[lr * (OSTR / 4) + 2 + col4] = ((const float4*)(xp + g * WW))[col4];
    }
    __syncthreads();

    float W1[15], W2[15], W3[9];
    #pragma unroll
    for (int k = 0; k < 15; ++k) { W1[k] = w1[c * 15 + k]; W2[k] = w2[c * 15 + k]; }
    #pragma unroll
    for (int k = 0; k < 9; ++k) W3[k] = w3[c * 9 + k];
    float bb1 = b1[c], ss1 = s1[c], gg1 = g1[c];
    float bb2 = b2[c], ss2 = s2[c], gg2 = g2[c];
    float bb3 = b3[c], ss3 = s3[c], gg3 = g3[c];

    const float4* XS4 = (const float4*)xs;
    int oct = threadIdx.x & 15;
    int row = threadIdx.x >> 4;
    int w0  = oct * 8;
    int lr  = row + OB_HALO;
    int h   = bs + row;

    float hb[24];
    #pragma unroll
    for (int t = 0; t < 6; ++t) {
        float4 q = XS4[lr * (OSTR / 4) + 2 * oct + t];
        hb[4*t] = q.x; hb[4*t+1] = q.y; hb[4*t+2] = q.z; hb[4*t+3] = q.w;
    }
    float a1[8];
    #pragma unroll
    for (int j = 0; j < 8; ++j) {
        float s = 0.f;
        #pragma unroll
        for (int k = 0; k < 15; ++k) s += hb[j + 1 + k] * W1[k];
        a1[j] = s;
    }

    float a2[8] = {0.f,0.f,0.f,0.f,0.f,0.f,0.f,0.f};
    #pragma unroll
    for (int k = 0; k < 15; ++k) {
        float4 qa = XS4[(lr + k - 7) * (OSTR / 4) + 2 + 2 * oct];
        float4 qb = XS4[(lr + k - 7) * (OSTR / 4) + 3 + 2 * oct];
        a2[0] += qa.x * W2[k]; a2[1] += qa.y * W2[k]; a2[2] += qa.z * W2[k]; a2[3] += qa.w * W2[k];
        a2[4] += qb.x * W2[k]; a2[5] += qb.y * W2[k]; a2[6] += qb.z * W2[k]; a2[7] += qb.w * W2[k];
    }

    float a3[8] = {0.f,0.f,0.f,0.f,0.f,0.f,0.f,0.f};
    #pragma unroll
    for (int kh = 0; kh < 3; ++kh) {
        float m[16];
        #pragma unroll
        for (int t = 0; t < 4; ++t) {
            float4 q = XS4[(lr + kh - 1) * (OSTR / 4) + 1 + 2 * oct + t];
            m[4*t] = q.x; m[4*t+1] = q.y; m[4*t+2] = q.z; m[4*t+3] = q.w;
        }
        #pragma unroll
        for (int j = 0; j < 8; ++j)
            #pragma unroll
            for (int kw = 0; kw < 3; ++kw)
                a3[j] += m[j + kw + 3] * W3[kh * 3 + kw];
    }

    float o[8];
    #pragma unroll
    for (int j = 0; j < 8; ++j)
        o[j] = (a1[j] + bb1) * ss1 + gg1
             + (a2[j] + bb2) * ss2 + gg2
             + (a3[j] + bb3) * ss3 + gg3;
    float* dst = osum + (size_t)bc * HWN + h * WW + w0;
    ((float4*)dst)[0] = make_float4(o[0], o[1], o[2], o[3]);
    ((float4*)dst)[1] = make_float4(o[4], o[5], o[6], o[7]);
}

// Stage 2 (LDS-tiled, 64-px tiles): off2[b][k][hw] = float2{oy,ox} PAIRED planes.
// Wave og owns pair-set: og0:{0,4,8} og1:{1,5} og2:{2,6} og3:{3,7}.
__global__ __launch_bounds__(256) void off_kernel(const float* __restrict__ osum,
    const float* __restrict__ balw, const float* __restrict__ balb,
    const float* __restrict__ s4, const float* __restrict__ g4,
    float2* __restrict__ off2)
{
    __shared__ float ls[CC * 64];   // 16 KB
    int bid = blockIdx.x;           // < 512
    int b   = bid >> 8;
    int hw0 = (bid & 255) * 64;

    const float* src = osum + (size_t)b * CHW + hw0;
    #pragma unroll
    for (int i = 0; i < 4; ++i) {
        int idx = threadIdx.x + i * 256;      // < 1024 float4
        int row = idx >> 4, col4 = idx & 15;
        ((float4*)ls)[row * 16 + col4] = *(const float4*)(src + (size_t)row * HWN + col4 * 4);
    }
    __syncthreads();

    int px = threadIdx.x & 63;
    int og = __builtin_amdgcn_readfirstlane((int)(threadIdx.x >> 6));  // 0..3
    int np = (og == 0) ? 3 : 2;

    float accy[3] = {0.f, 0.f, 0.f};
    float accx[3] = {0.f, 0.f, 0.f};
    for (int ic = 0; ic < CC; ++ic) {
        float v = ls[ic * 64 + px];
        #pragma unroll
        for (int j = 0; j < 3; ++j)
            if (j < np) {
                int k = og + j * 4;                       // uniform -> s_load weights
                accy[j] += v * balw[(2 * k)     * CC + ic];
                accx[j] += v * balw[(2 * k + 1) * CC + ic];
            }
    }
    #pragma unroll
    for (int j = 0; j < 3; ++j)
        if (j < np) {
            int k = og + j * 4;
            int ocy = 2 * k, ocx = 2 * k + 1;
            float2 o;
            o.x = (accy[j] + balb[ocy]) * s4[ocy] + g4[ocy];
            o.y = (accx[j] + balb[ocx]) * s4[ocx] + g4[ocx];
            off2[((size_t)b * 9 + k) * HWN + hw0 + px] = o;
        }
}

// zero-padded global gather (exact: reference mask*clamp == zero-pad sampling)
__device__ __forceinline__ float gz(const float* __restrict__ xp, int y, int x) {
    return ((unsigned)y < (unsigned)HH && (unsigned)x < (unsigned)WW) ? xp[y * WW + x] : 0.f;
}

// Stage 3: deformable gather. 2 ch/block (float2-interleaved LDS), zero-padded
// tile, frac shared across dilations, paired float2 offsets (9 loads/px),
// pad-only zero-fill + single barrier on interior bands, compile-time ds offsets.
// bid low 4 bits = band -> XCD = band%8 locality.
__global__ __launch_bounds__(256) void deform_kernel(
    const float* __restrict__ x,
    const float2* __restrict__ off2,
    const float* __restrict__ dw2, const float* __restrict__ dw3,
    const float* __restrict__ dw4, const float* __restrict__ dw5,
    float* __restrict__ pre)
{
    __shared__ float xs[LROWS * XSTR * CPB];   // 27648 B

    int bid  = blockIdx.x;                     // < 1024
    int band = bid & (NBAND - 1);
    int bcp  = bid >> 4;
    int cp   = bcp & 31;
    int b    = bcp >> 5;
    int c0   = cp * CPB;
    int bc0  = b * CC + c0;

    int r_lo_v = band * BAND_H - HALO;
    const float* xp0 = x + (size_t)bc0 * HWN;
    const float* xp1 = xp0 + HWN;

    bool interior = (r_lo_v >= 0) && (r_lo_v + LROWS <= HH);   // bands 1..14
    if (interior) {
        // pad columns only (texels 0..7, 136..143 per row): 192 float4 zero-stores
        if (threadIdx.x < 192) {
            int lr = threadIdx.x >> 3, q = threadIdx.x & 7;
            int tc = (q < 4) ? q : 64 + q;
            ((float4*)xs)[lr * (XSTR / 2) + tc] = make_float4(0.f, 0.f, 0.f, 0.f);
        }
        for (int i = threadIdx.x; i < LROWS * (WW / 4); i += 256) {
            int r = i >> 5, col4 = i & 31;
            int g = r_lo_v + r;
            float4 q0 = ((const float4*)(xp0 + g * WW))[col4];
            float4 q1 = ((const float4*)(xp1 + g * WW))[col4];
            ((float4*)xs)[r * (XSTR / 2) + XPAD / 2 + col4 * 2]     = make_float4(q0.x, q1.x, q0.y, q1.y);
            ((float4*)xs)[r * (XSTR / 2) + XPAD / 2 + col4 * 2 + 1] = make_float4(q0.z, q1.z, q0.w, q1.w);
        }
        __syncthreads();                       // single barrier (regions disjoint)
    } else {
        for (int i = threadIdx.x; i < (LROWS * XSTR * CPB) / 4; i += 256)
            ((float4*)xs)[i] = make_float4(0.f, 0.f, 0.f, 0.f);
        __syncthreads();
        int gstart = r_lo_v < 0 ? 0 : r_lo_v;
        int gend   = r_lo_v + LROWS; if (gend > HH) gend = HH;
        int nitems = (gend - gstart) * (WW / 4);
        for (int i = threadIdx.x; i < nitems; i += 256) {
            int r = i >> 5, col4 = i & 31;
            int g = gstart + r;
            int lr = g - r_lo_v;
            float4 q0 = ((const float4*)(xp0 + g * WW))[col4];
            float4 q1 = ((const float4*)(xp1 + g * WW))[col4];
            ((float4*)xs)[lr * (XSTR / 2) + XPAD / 2 + col4 * 2]     = make_float4(q0.x, q1.x, q0.y, q1.y);
            ((float4*)xs)[lr * (XSTR / 2) + XPAD / 2 + col4 * 2 + 1] = make_float4(q0.z, q1.z, q0.w, q1.w);
        }
        __syncthreads();
    }

    const float2* XS2 = (const float2*)xs;
    const float2* offb = off2 + (size_t)b * 9 * HWN;

    #pragma unroll 1
    for (int chunk = 0; chunk < (BAND_H * WW) / 256; ++chunk) {
        int p = band * (BAND_H * WW) + chunk * 256 + (int)threadIdx.x;
        float hf = (float)(p >> 7);
        float wf = (float)(p & (WW - 1));

        float2 ofk[9];
        #pragma unroll
        for (int k = 0; k < 9; ++k)                    // paired planar, coalesced 8B
            ofk[k] = offb[(size_t)k * HWN + p];

        float acc0 = 0.f, acc1 = 0.f;
        #pragma unroll
        for (int k = 0; k < 9; ++k) {
            const int ky = k / 3 - 1, kx = k % 3 - 1;
            float pyb = ofk[k].x + hf;
            float pxb = ofk[k].y + wf;
            float y0f = floorf(pyb), x0f = floorf(pxb);
            float wy = pyb - y0f, wx = pxb - x0f;
            int y0g = (int)y0f, x0g = (int)x0f;
            int y0b = y0g - r_lo_v;
            int x0b = x0g + XPAD;
            float cxa = 1.f - wx, cxb = wx;

            const int dkyLo = (ky < 0) ? -5 : (ky > 0 ? 2 : 0);
            const int dkyHi = (ky < 0) ? -2 : (ky > 0 ? 5 : 0);
            const int dkxLo = (kx < 0) ? -5 : (kx > 0 ? 2 : 0);
            const int dkxHi = (kx < 0) ? -2 : (kx > 0 ? 5 : 0);
            bool ok = (y0b + dkyLo >= 0) & (y0b + dkyHi <= LROWS - 2)
                    & (x0b + dkxLo >= 0) & (x0b + dkxHi <= XSTR - 2);

            if (ok) {
                const float2* pb = XS2 + (y0b * XSTR + x0b);   // one vaddr per k
                #pragma unroll
                for (int di = 0; di < 4; ++di) {
                    const int d  = di + 2;
                    const int st = d * (ky * XSTR + kx);       // compile-time imm
                    float2 a  = pb[st],        bq = pb[st + 1];
                    float2 cq = pb[st + XSTR], dq = pb[st + XSTR + 1];
                    float ra0 = cxa * a.x + cxb * bq.x;
                    float rb0 = cxa * cq.x + cxb * dq.x;
                    float ra1 = cxa * a.y + cxb * bq.y;
                    float rb1 = cxa * cq.y + cxb * dq.y;
                    float s0 = ra0 + wy * (rb0 - ra0);
                    float s1 = ra1 + wy * (rb1 - ra1);
                    const float* dwp = (di == 0) ? dw2 : (di == 1) ? dw3 : (di == 2) ? dw4 : dw5;
                    acc0 += s0 * dwp[c0 * 9 + k];              // block-uniform -> s_load
                    acc1 += s1 * dwp[(c0 + 1) * 9 + k];
                }
            } else {                                           // rare outlier: global zero-pad
                #pragma unroll
                for (int di = 0; di < 4; ++di) {
                    const int d = di + 2;
                    int yy = y0g + d * ky, xx = x0g + d * kx;
                    float v00 = gz(xp0, yy, xx),     v01 = gz(xp0, yy, xx + 1);
                    float v10 = gz(xp0, yy + 1, xx), v11 = gz(xp0, yy + 1, xx + 1);
                    float u00 = gz(xp1, yy, xx),     u01 = gz(xp1, yy, xx + 1);
                    float u10 = gz(xp1, yy + 1, xx), u11 = gz(xp1, yy + 1, xx + 1);
                    float s0 = (1.f - wy) * (cxa * v00 + cxb * v01) + wy * (cxa * v10 + cxb * v11);
                    float s1 = (1.f - wy) * (cxa * u00 + cxb * u01) + wy * (cxa * u10 + cxb * u11);
                    const float* dwp = (di == 0) ? dw2 : (di == 1) ? dw3 : (di == 2) ? dw4 : dw5;
                    acc0 += s0 * dwp[c0 * 9 + k];
                    acc1 += s1 * dwp[(c0 + 1) * 9 + k];
                }
            }
        }
        pre[((size_t)bc0 << 14) + p]       = acc0;
        pre[((size_t)(bc0 + 1) << 14) + p] = acc1;
    }
}

// Stage 4 (LDS-tiled): out = (BN(bias(1x1conv(pre, fin_w)))) * x
__global__ __launch_bounds__(256) void final_kernel(const float* __restrict__ pre,
    const float* __restrict__ finw, const float* __restrict__ finb,
    const float* __restrict__ s5, const float* __restrict__ g5,
    const float* __restrict__ x, float* __restrict__ out)
{
    __shared__ float ls[CC * 64];   // 16 KB
    int bid = blockIdx.x;           // < 512
    int b   = bid >> 8;
    int hw0 = (bid & 255) * 64;

    const float* src = pre + (size_t)b * CHW + hw0;
    #pragma unroll
    for (int i = 0; i < 4; ++i) {
        int idx = threadIdx.x + i * 256;      // < 1024 float4
        int row = idx >> 4, col4 = idx & 15;
        ((float4*)ls)[row * 16 + col4] = *(const float4*)(src + (size_t)row * HWN + col4 * 4);
    }
    __syncthreads();

    int hw = threadIdx.x & 63;
    int og = __builtin_amdgcn_readfirstlane((int)(threadIdx.x >> 6));  // 0..3

    float acc[16];
    #pragma unroll
    for (int j = 0; j < 16; ++j) acc[j] = 0.f;
    for (int ic = 0; ic < CC; ++ic) {
        float v = ls[ic * 64 + hw];
        #pragma unroll
        for (int j = 0; j < 16; ++j)
            acc[j] += v * finw[(og * 16 + j) * CC + ic];   // uniform -> s_load
    }
    #pragma unroll
    for (int j = 0; j < 16; ++j) {
        int oc = og * 16 + j;
        size_t oidx = ((size_t)(b * CC + oc) << 14) + hw0 + hw;
        out[oidx] = ((acc[j] + finb[oc]) * s5[oc] + g5[oc]) * x[oidx];
    }
}

extern "C" void kernel_launch(void* const* d_in, const int* in_sizes, int n_in,
                              void* d_out, int out_size, void* d_ws, size_t ws_size,
                              hipStream_t stream) {
    const float* x      = (const float*)d_in[0];
    const float* off1_w = (const float*)d_in[1];
    const float* off1_b = (const float*)d_in[2];
    const float* bn1_s  = (const float*)d_in[3];
    const float* bn1_b  = (const float*)d_in[4];
    const float* off2_w = (const float*)d_in[5];
    const float* off2_b = (const float*)d_in[6];
    const float* bn2_s  = (const float*)d_in[7];
    const float* bn2_b  = (const float*)d_in[8];
    const float* off3_w = (const float*)d_in[9];
    const float* off3_b = (const float*)d_in[10];
    const float* bn3_s  = (const float*)d_in[11];
    const float* bn3_b  = (const float*)d_in[12];
    const float* bal_w  = (const float*)d_in[13];
    const float* bal_b  = (const float*)d_in[14];
    const float* bn4_s  = (const float*)d_in[15];
    const float* bn4_b  = (const float*)d_in[16];
    const float* dw2    = (const float*)d_in[17];
    const float* dw3    = (const float*)d_in[18];
    const float* dw4    = (const float*)d_in[19];
    const float* dw5    = (const float*)d_in[20];
    const float* fin_w  = (const float*)d_in[21];
    const float* fin_b  = (const float*)d_in[22];
    const float* bn5_s  = (const float*)d_in[23];
    const float* bn5_b  = (const float*)d_in[24];

    float* ws   = (float*)d_ws;
    float* osum = ws;                              // 8 MB
    float2* off2 = (float2*)(ws + (size_t)BB * CHW);  // 2.25 MB (9 paired planes)
    float* pre  = ws + (size_t)BB * CHW + (size_t)BB * 18 * HWN;  // 8 MB

    float* out = (float*)d_out;

    osum_kernel<<<BB * CC * (HH / OB_H), 256, 0, stream>>>(x,
        off1_w, off1_b, bn1_s, bn1_b,
        off2_w, off2_b, bn2_s, bn2_b,
        off3_w, off3_b, bn3_s, bn3_b, osum);
    off_kernel<<<BB * (HWN / 64), 256, 0, stream>>>(osum, bal_w, bal_b, bn4_s, bn4_b, off2);
    deform_kernel<<<BB * (CC / CPB) * NBAND, 256, 0, stream>>>(x, off2, dw2, dw3, dw4, dw5, pre);
    final_kernel<<<BB * (HWN / 64), 256, 0, stream>>>(pre, fin_w, fin_b, bn5_s, bn5_b, x, out);
}